// Round 6
// baseline (10927.959 us; speedup 1.0000x reference)
//
#include <hip/hip_runtime.h>
#include <math.h>

#define DEV __device__ __forceinline__

static constexpr int B_ = 128, T_ = 32, H_ = 512;
static constexpr int S_ = 2048, M_ = 64, OUT_ = 256;
static constexpr float EPSF = 1e-8f;

DEV float sigmoidf_(float x){ return 1.0f/(1.0f+expf(-x)); }
DEV float softplusf_(float x){ return fmaxf(x,0.0f) + log1pf(expf(-fabsf(x))); }

// ---------------- preamble: mem [B,S,M] -> memT [B,M,S] ----------------
__global__ __launch_bounds__(256)
void k_transpose_mem(const float* __restrict__ mem, float* __restrict__ memT){
  const int b = blockIdx.x, sc = blockIdx.y;   // sc < 64 (32-slot chunks)
  __shared__ float tile[32*65];
  const float* src = mem + ((size_t)b*S_ + (size_t)sc*32)*M_;
  #pragma unroll
  for(int p=0;p<8;p++){
    int idx = threadIdx.x + p*256;     // 0..2047 = i*64+m
    int i = idx>>6, m = idx&63;
    tile[i*65+m] = src[idx];
  }
  __syncthreads();
  float* dst = memT + (size_t)b*M_*S_ + (size_t)sc*32;
  #pragma unroll
  for(int p=0;p<8;p++){
    int idx = threadIdx.x + p*256;
    int m = idx>>5, i = idx&31;
    dst[(size_t)m*S_ + i] = tile[i*65+m];
  }
}

// ---------------- preamble: W_rd [256,256] -> W_rdT ----------------
__global__ __launch_bounds__(256)
void k_transpose_rd(const float* __restrict__ W, float* __restrict__ WT){
  int idx = blockIdx.x*256 + threadIdx.x;  // 65536
  int k = idx>>8, o = idx&255;
  WT[k*256+o] = W[o*256+k];
}

// ---------------- preamble GEMM: xg = x @ W_ih^T + (b_ih+b_hh) ----------------
__global__ __launch_bounds__(256)
void k_gemm_xg(const float* __restrict__ A, const float* __restrict__ Bm,
               float* __restrict__ C,
               const float* __restrict__ bias0, const float* __restrict__ bias1)
{
  const int BM=64, BN=64, BK=16;  // A [4096,256], Bm [2048,256], C [4096,2048]
  __shared__ float As[BK*BM];
  __shared__ float Bs[BK*BN];
  const int m0 = blockIdx.x*BM, n0 = blockIdx.y*BN;
  const int tid = threadIdx.x;
  const int tx = tid & 15, ty = tid >> 4;
  float acc[4][4] = {};
  const int row = tid >> 2, kk = (tid & 3) * 4;
  for(int k0 = 0; k0 < 256; k0 += BK){
    float4 av = *(const float4*)(A  + (size_t)(m0+row)*256 + k0 + kk);
    float4 bv = *(const float4*)(Bm + (size_t)(n0+row)*256 + k0 + kk);
    As[(kk+0)*BM+row]=av.x; As[(kk+1)*BM+row]=av.y; As[(kk+2)*BM+row]=av.z; As[(kk+3)*BM+row]=av.w;
    Bs[(kk+0)*BN+row]=bv.x; Bs[(kk+1)*BN+row]=bv.y; Bs[(kk+2)*BN+row]=bv.z; Bs[(kk+3)*BN+row]=bv.w;
    __syncthreads();
    #pragma unroll
    for(int k=0;k<BK;k++){
      float4 a = *(const float4*)&As[k*BM + 4*ty];
      float4 b = *(const float4*)&Bs[k*BN + 4*tx];
      acc[0][0]+=a.x*b.x; acc[0][1]+=a.x*b.y; acc[0][2]+=a.x*b.z; acc[0][3]+=a.x*b.w;
      acc[1][0]+=a.y*b.x; acc[1][1]+=a.y*b.y; acc[1][2]+=a.y*b.z; acc[1][3]+=a.y*b.w;
      acc[2][0]+=a.z*b.x; acc[2][1]+=a.z*b.y; acc[2][2]+=a.z*b.z; acc[2][3]+=a.z*b.w;
      acc[3][0]+=a.w*b.x; acc[3][1]+=a.w*b.y; acc[3][2]+=a.w*b.z; acc[3][3]+=a.w*b.w;
    }
    __syncthreads();
  }
  #pragma unroll
  for(int i=0;i<4;i++){
    int m = m0 + 4*ty + i;
    int n = n0 + 4*tx;
    float4 o; o.x=acc[i][0]; o.y=acc[i][1]; o.z=acc[i][2]; o.w=acc[i][3];
    o.x += bias0[n]+bias1[n];     o.y += bias0[n+1]+bias1[n+1];
    o.z += bias0[n+2]+bias1[n+2]; o.w += bias0[n+3]+bias1[n+3];
    *(float4*)(C + (size_t)m*2048 + n) = o;
  }
}

// ================= batch-parallel persistent kernel =================
// One block per batch. All recurrent state in LDS; only block-local syncs.
// Weights are read-only (stay hot in XCD L2; never invalidated).
__global__ __launch_bounds__(512,1)
void k_dnc(const float* __restrict__ xg,    const float* __restrict__ Whh,
           const float* __restrict__ h0,    const float* __restrict__ c0,
           const float* __restrict__ Wout,  const float* __restrict__ bout,
           const float* __restrict__ Whead, const float* __restrict__ bhead,
           const float* __restrict__ WrdT,  const float* __restrict__ b_rd,
           float* __restrict__ memT,        float* __restrict__ out)
{
  __shared__ float sh_h[512];
  __shared__ float sh_c[512];
  __shared__ float sg[2048];     // gate pre-activations
  __shared__ float sv[712];      // [vt(256) | ctrl(453) | pad]
  __shared__ float kkLDS[320];   // tanh'd keys: kr(256) + kw(64)
  __shared__ float coef[8];      // beta/||k|| for 5 heads
  __shared__ float ss[5*2048];   // logits, head-major
  __shared__ float er[64], ad[64];
  __shared__ float nv[512];      // updated mem at 8 write slots
  __shared__ float wval[8];
  __shared__ float fix[32];
  __shared__ float readsv[256];
  __shared__ int   widx[8];

  const int b    = blockIdx.x;
  const int tid  = threadIdx.x;          // 512 threads = 8 waves
  const int lane = tid & 63, wave = tid >> 6;
  const int sub  = lane & 7;             // k-segment id (8-lane split)
  const int riw  = lane >> 3;            // row-in-wave (0..7)

  // init state
  sh_h[tid] = h0[(size_t)b*512 + tid];
  sh_c[tid] = c0[(size_t)b*512 + tid];
  __syncthreads();

  // h chunk cache: hc[q] = sh_h[q*32 + sub*4 .. +4)
  float4 hc[16];
  #pragma unroll
  for(int q=0;q<16;q++) hc[q] = *(const float4*)&sh_h[q*32 + sub*4];

  float* memB = memT + (size_t)b*(size_t)(M_*S_);

  for(int t=0;t<T_;t++){
    // ---- gates: sg[j] = dot(h, Whh[j]) ; 8 lanes per row, coalesced 128B lines
    for(int p=0;p<32;p++){
      const int j = p*64 + wave*8 + riw;
      const float* wr = Whh + (size_t)j*512;
      float acc = 0.f;
      #pragma unroll
      for(int q=0;q<16;q++){
        float4 w = *(const float4*)(wr + q*32 + sub*4);
        acc += w.x*hc[q].x + w.y*hc[q].y + w.z*hc[q].z + w.w*hc[q].w;
      }
      acc += __shfl_xor(acc, 1);
      acc += __shfl_xor(acc, 2);
      acc += __shfl_xor(acc, 4);
      if(sub == 0) sg[j] = acc;
    }
    __syncthreads();

    // ---- LSTM elementwise (gate order i,f,g,o); xg already has biases
    {
      const float* xr = xg + ((size_t)b*T_ + t)*(size_t)(4*H_);
      const int j = tid;
      float gi = sg[j]      + xr[j];
      float gf = sg[512+j]  + xr[512+j];
      float gg = sg[1024+j] + xr[1024+j];
      float go = sg[1536+j] + xr[1536+j];
      float cc = sigmoidf_(gf)*sh_c[j] + sigmoidf_(gi)*tanhf(gg);
      float hh = sigmoidf_(go)*tanhf(cc);
      sh_c[j] = cc; sh_h[j] = hh;
    }
    __syncthreads();

    // reload h chunk (used by vc now and by gates next step)
    #pragma unroll
    for(int q=0;q<16;q++) hc[q] = *(const float4*)&sh_h[q*32 + sub*4];

    // ---- vc[0:709] = h @ cat(W_out, W_head)^T + bias ; rows 709..711 = 0
    for(int p=0;p<12;p++){
      const int j = p*64 + wave*8 + riw;
      if(j < 712){
        float res = 0.f;
        if(j < 709){
          const float* wr = (j < 256) ? (Wout + (size_t)j*512)
                                      : (Whead + (size_t)(j-256)*512);
          float acc = 0.f;
          #pragma unroll
          for(int q=0;q<16;q++){
            float4 w = *(const float4*)(wr + q*32 + sub*4);
            acc += w.x*hc[q].x + w.y*hc[q].y + w.z*hc[q].z + w.w*hc[q].w;
          }
          acc += __shfl_xor(acc, 1);
          acc += __shfl_xor(acc, 2);
          acc += __shfl_xor(acc, 4);
          res = acc + ((j < 256) ? bout[j] : bhead[j-256]);
        } else {
          // keep the shuffles exec-uniform within the 8-group: j>=709 only when
          // whole 8-group is >=709? no — j varies by riw, sub-uniform. safe:
          res = 0.f;
        }
        if(sub == 0) sv[j] = res;
      }
    }
    __syncthreads();

    // ---- key transforms
    if(tid < 256) kkLDS[tid] = tanhf(sv[256+tid]);                 // kr
    else if(tid < 320) kkLDS[tid] = tanhf(sv[260+tid]);            // kw (516+(tid-256))
    if(tid < 64){ er[tid] = sigmoidf_(sv[581+tid]); ad[tid] = tanhf(sv[645+tid]); }
    __syncthreads();
    if(tid < 5){
      float s = 0.f;
      #pragma unroll
      for(int m=0;m<64;m++){ float x = kkLDS[tid*64+m]; s += x*x; }
      float beta = softplusf_( tid<4 ? sv[512+tid] : sv[580] );
      coef[tid] = beta / fmaxf(sqrtf(s), EPSF);
    }
    __syncthreads();

    // ---- scores over OLD mem: 4 slots per thread
    {
      float nrm[4] = {}, d0[4] = {}, d1[4] = {}, d2[4] = {}, d3[4] = {}, dw[4] = {};
      for(int m=0;m<64;m++){
        float k0 = kkLDS[m], k1 = kkLDS[64+m], k2 = kkLDS[128+m],
              k3 = kkLDS[192+m], k4 = kkLDS[256+m];
        const float* row = memB + (size_t)m*S_ + tid;
        #pragma unroll
        for(int r=0;r<4;r++){
          float x = row[r*512];
          nrm[r] += x*x;
          d0[r] += x*k0; d1[r] += x*k1; d2[r] += x*k2; d3[r] += x*k3; dw[r] += x*k4;
        }
      }
      #pragma unroll
      for(int r=0;r<4;r++){
        const int s = tid + r*512;
        float inv = 1.0f / fmaxf(sqrtf(nrm[r]), EPSF);
        ss[0*2048+s] = coef[0]*d0[r]*inv;
        ss[1*2048+s] = coef[1]*d1[r]*inv;
        ss[2*2048+s] = coef[2]*d2[r]*inv;
        ss[3*2048+s] = coef[3]*d3[r]*inv;
        ss[4*2048+s] = coef[4]*dw[r]*inv;
      }
    }
    __syncthreads();

    // ---- write head: softmax stats + top-8 (wave 0 only)
    if(tid < 64){
      const float* sw = &ss[4*2048];
      float loc[32];
      #pragma unroll
      for(int j=0;j<32;j++) loc[j] = sw[lane + j*64];
      float mx = -INFINITY;
      #pragma unroll
      for(int j=0;j<32;j++) mx = fmaxf(mx, loc[j]);
      #pragma unroll
      for(int off=32; off; off>>=1) mx = fmaxf(mx, __shfl_down(mx, off));
      mx = __shfl(mx, 0);
      float sum = 0.f;
      #pragma unroll
      for(int j=0;j<32;j++) sum += expf(loc[j]-mx);
      #pragma unroll
      for(int off=32; off; off>>=1) sum += __shfl_down(sum, off);
      sum = __shfl(sum, 0);
      float invZ = 1.0f / sum;
      for(int p=0;p<8;p++){
        float bv = -INFINITY; int bi = 0x7fffffff;
        #pragma unroll
        for(int j=0;j<32;j++){
          float x = loc[j];
          if(x > bv){ bv = x; bi = j*64 + lane; }
        }
        #pragma unroll
        for(int off=32; off; off>>=1){
          float ov = __shfl_down(bv, off); int oi = __shfl_down(bi, off);
          if(ov > bv || (ov == bv && oi < bi)){ bv = ov; bi = oi; }
        }
        bv = __shfl(bv, 0); bi = __shfl(bi, 0);
        if(lane == 0){ widx[p] = bi; wval[p] = expf(bv-mx)*invZ; }
        if((bi & 63) == lane){
          int pos = bi >> 6;
          #pragma unroll
          for(int q=0;q<32;q++) if(q == pos) loc[q] = -INFINITY;
        }
      }
    }
    __syncthreads();

    // ---- rank-1 erase/add at the 8 write slots (512 threads = 8 slots x 64 dims)
    {
      int j = tid >> 6, m = tid & 63;
      int s = widx[j];
      float w = wval[j];
      size_t ptr = (size_t)m*S_ + s;
      float old = memB[ptr];
      float x = old * (1.0f - w*er[m]) + w*ad[m];
      memB[ptr] = x;
      nv[j*64+m] = x;
    }
    __syncthreads();

    // ---- recompute read logits at the 8 updated slots (waves 0..3)
    if(tid < 256){
      #pragma unroll
      for(int q=0;q<2;q++){
        int sl = wave*2 + q;
        float x = nv[sl*64 + lane];
        float n2 = x*x;
        #pragma unroll
        for(int off=32; off; off>>=1) n2 += __shfl_down(n2, off);
        n2 = __shfl(n2, 0);
        float invmn = 1.0f / fmaxf(sqrtf(n2), EPSF);
        #pragma unroll
        for(int r=0;r<4;r++){
          float d = x * kkLDS[r*64+lane];
          #pragma unroll
          for(int off=32; off; off>>=1) d += __shfl_down(d, off);
          if(lane == 0) fix[r*8+sl] = coef[r] * d * invmn;
        }
      }
    }
    __syncthreads();

    // ---- read heads: one wave per head (waves 0..3)
    if(tid < 256){
      const int r = wave;
      const float* sr = &ss[r*2048];
      float loc[32];
      #pragma unroll
      for(int j=0;j<32;j++) loc[j] = sr[lane + j*64];
      #pragma unroll
      for(int p=0;p<8;p++){
        int s = widx[p];
        if((s & 63) == lane){
          int pos = s >> 6; float f = fix[r*8+p];
          #pragma unroll
          for(int q=0;q<32;q++) if(q == pos) loc[q] = f;
        }
      }
      float mx = -INFINITY;
      #pragma unroll
      for(int j=0;j<32;j++) mx = fmaxf(mx, loc[j]);
      #pragma unroll
      for(int off=32; off; off>>=1) mx = fmaxf(mx, __shfl_down(mx, off));
      mx = __shfl(mx, 0);
      float sum = 0.f;
      #pragma unroll
      for(int j=0;j<32;j++) sum += expf(loc[j]-mx);
      #pragma unroll
      for(int off=32; off; off>>=1) sum += __shfl_down(sum, off);
      sum = __shfl(sum, 0);
      float invZ = 1.0f / sum;
      float acc = 0.f;                  // lane == mem dim m
      const float* rowp = memB + (size_t)lane*S_;
      for(int p=0;p<8;p++){
        float bv = -INFINITY; int bi = 0x7fffffff;
        #pragma unroll
        for(int j=0;j<32;j++){
          float x = loc[j];
          if(x > bv){ bv = x; bi = j*64 + lane; }
        }
        #pragma unroll
        for(int off=32; off; off>>=1){
          float ov = __shfl_down(bv, off); int oi = __shfl_down(bi, off);
          if(ov > bv || (ov == bv && oi < bi)){ bv = ov; bi = oi; }
        }
        bv = __shfl(bv, 0); bi = __shfl(bi, 0);
        if((bi & 63) == lane){
          int pos = bi >> 6;
          #pragma unroll
          for(int q=0;q<32;q++) if(q == pos) loc[q] = -INFINITY;
        }
        float w = expf(bv-mx)*invZ;
        acc += w * rowp[bi];
      }
      readsv[r*64+lane] = acc;
    }
    __syncthreads();

    // ---- output: out[b,t,o] = vt[o] + reads @ W_rd^T + b_rd
    if(tid < 256){
      const int o = tid;
      float acc = sv[o] + b_rd[o];
      #pragma unroll 4
      for(int k=0;k<256;k++) acc += readsv[k] * WrdT[k*256+o];
      out[((size_t)b*T_ + t)*(size_t)OUT_ + o] = acc;
    }
    __syncthreads();
  }
}

// ---------------- host ----------------
extern "C" void kernel_launch(void* const* d_in, const int* in_sizes, int n_in,
                              void* d_out, int out_size, void* d_ws, size_t ws_size,
                              hipStream_t stream)
{
  const float* x     = (const float*)d_in[0];
  const float* h0    = (const float*)d_in[1];
  const float* c0    = (const float*)d_in[2];
  const float* mem0  = (const float*)d_in[3];
  const float* W_ih  = (const float*)d_in[4];
  const float* W_hh  = (const float*)d_in[5];
  const float* b_ih  = (const float*)d_in[6];
  const float* b_hh  = (const float*)d_in[7];
  const float* W_out = (const float*)d_in[8];
  const float* b_out = (const float*)d_in[9];
  const float* W_rd  = (const float*)d_in[10];
  const float* b_rd  = (const float*)d_in[11];
  const float* W_head= (const float*)d_in[12];
  const float* b_head= (const float*)d_in[13];
  float* out = (float*)d_out;

  float* ws   = (float*)d_ws;
  float* memT = ws;                    // 128*64*2048 = 16,777,216
  float* xg   = memT + 16777216;       // 128*32*2048 =  8,388,608
  float* WrdT = xg   + 8388608;        // 256*256     =     65,536
  const size_t need = (size_t)(16777216 + 8388608 + 65536) * sizeof(float);
  if(ws_size < need) return;  // ~101 MB workspace required

  k_transpose_mem<<<dim3(128,64),256,0,stream>>>(mem0, memT);
  k_transpose_rd<<<256,256,0,stream>>>(W_rd, WrdT);
  k_gemm_xg<<<dim3(64,32),256,0,stream>>>(x, W_ih, xg, b_ih, b_hh);

  k_dnc<<<128,512,0,stream>>>(xg, W_hh, h0, c0,
                              W_out, b_out, W_head, b_head,
                              WrdT, b_rd, memT, out);
}